// Round 14
// baseline (229.201 us; speedup 1.0000x reference)
//
#include <hip/hip_runtime.h>

#define TT  200
#define IN  5
#define NH  32
#define FC1 20
#define CH  64
#define RSG 12          // h20 row stride in dwords (48 B)

// ws layout (dword units):
//  [0,2048):      whh f16 pairs, lane-packed: l*32 + m*8 + j
//                 lane l=(u,p): row (l&31)+32m, dims (16p+2j, 16p+2j+1)
//  [2048,7168):   wih f16 pairs, lane-packed: l*20 + m*5 + jj
//                 lane l=(u,p): row (l&31)+32m, dims (10p+2jj, 10p+2jj+1)
//  [7168,7296):   bias f32[128] = b_ih + b_hh
//  [8192, ...):   h20 table (GH path): row r=b*TT+t, 12 dwords (10 h2 pairs)
#define WS_WHH  0
#define WS_WIH  2048
#define WS_BIAS 7168
#define WS_H20  8192

typedef _Float16 h2t __attribute__((ext_vector_type(2)));

#if __has_builtin(__builtin_amdgcn_fdot2)
#define FDOT2(a, b, c) __builtin_amdgcn_fdot2((a), (b), (c), false)
#else
__device__ __forceinline__ float FDOT2(h2t a, h2t b, float c) {
    return fmaf((float)a.x, (float)b.x, fmaf((float)a.y, (float)b.y, c));
}
#endif

__device__ __forceinline__ float sigm(float a) {
    return __builtin_amdgcn_rcpf(1.f + __expf(-a));
}
__device__ __forceinline__ float tanh_f(float a) {
    return fmaf(2.f, __builtin_amdgcn_rcpf(1.f + __expf(-2.f * a)), -1.f);
}
__device__ __forceinline__ h2t bc_h2(unsigned int v) {
    return __builtin_bit_cast(h2t, v);
}
__device__ __forceinline__ unsigned int h2bits(float a, float b) {
    return __builtin_bit_cast(unsigned int, h2t{(_Float16)a, (_Float16)b});
}

// ---- prep: pack whh/wih (lane layouts) + bias into ws (r13-proven) ----
__global__ __launch_bounds__(256) void prep_w(
    const float* __restrict__ w_ih, const float* __restrict__ w_hh,
    const float* __restrict__ b_ih, const float* __restrict__ b_hh,
    unsigned int* __restrict__ ws)
{
    const int tid = blockIdx.x * 256 + threadIdx.x;
    if (tid < 2048) {
        const int l = tid >> 5, k = tid & 31;
        const int m = k >> 3, j = k & 7;
        const int row = (l & 31) + 32 * m;
        const int d0  = 16 * (l >> 5) + 2 * j;
        ws[WS_WHH + tid] = h2bits(w_hh[row * NH + d0], w_hh[row * NH + d0 + 1]);
    } else if (tid < 7168) {
        const int t2 = tid - WS_WIH;
        const int l = t2 / 20, k = t2 % 20;
        const int m = k / 5, jj = k % 5;
        const int row = (l & 31) + 32 * m;
        const int d0  = 10 * (l >> 5) + 2 * jj;
        ws[WS_WIH + t2] = h2bits(w_ih[row * FC1 + d0], w_ih[row * FC1 + d0 + 1]);
    } else if (tid < 7296) {
        const int r = tid - WS_BIAS;
        ((float*)(ws + WS_BIAS))[r] = b_ih[r] + b_hh[r];
    }
}

// ---- prep (GH path): h20[b,t] = relu(fc1(x[b,t])) for all rows ----
__global__ __launch_bounds__(256) void prep_h20(
    const float* __restrict__ x, const float* __restrict__ fc1_w,
    const float* __restrict__ fc1_b, unsigned int* __restrict__ ws, int nrows)
{
    const int r = blockIdx.x * 256 + threadIdx.x;
    if (r >= nrows) return;
    const float* xr = x + (size_t)r * IN;
    float xv[IN];
    #pragma unroll
    for (int i = 0; i < IN; ++i) xv[i] = xr[i];
    unsigned int ow[10];
    #pragma unroll
    for (int j = 0; j < FC1; j += 2) {
        float a0 = fc1_b[j], a1 = fc1_b[j + 1];
        #pragma unroll
        for (int i = 0; i < IN; ++i) {
            a0 = fmaf(fc1_w[j * IN + i],       xv[i], a0);
            a1 = fmaf(fc1_w[(j + 1) * IN + i], xv[i], a1);
        }
        ow[j >> 1] = h2bits(fmaxf(a0, 0.f), fmaxf(a1, 0.f));
    }
    unsigned int* dst = ws + WS_H20 + (size_t)r * RSG;
    *(uint4*)(dst)     = uint4{ow[0], ow[1], ow[2], ow[3]};
    *(uint4*)(dst + 4) = uint4{ow[4], ow[5], ow[6], ow[7]};
    *(uint2*)(dst + 8) = uint2{ow[8], ow[9]};
}

// One step, NO memory fences. h state ordering: ds ops on sh_h may-alias
// (same array) -> compiler keeps program order; same-wave DS is HW-FIFO.
// Combine across K-halves via shfl_xor (register op). Gate formulas are
// p-independent (both halves mirror the full i,f,g,o of dim u).
#define STEP(Q0, Q1, Q2)                                                      \
  {                                                                           \
    const uint4* hp_ = (const uint4*)((const char*)sh_h + 32 * p);            \
    uint4 h0_ = hp_[0], h1_ = hp_[1];                                         \
    h2t e0_ = bc_h2(p ? (Q1).y : (Q0).x);                                     \
    h2t e1_ = bc_h2(p ? (Q1).z : (Q0).y);                                     \
    h2t e2_ = bc_h2(p ? (Q1).w : (Q0).z);                                     \
    h2t e3_ = bc_h2(p ? (Q2).x : (Q0).w);                                     \
    h2t e4_ = bc_h2(p ? (Q2).y : (Q1).x);                                     \
    float dA_[4];                                                             \
    _Pragma("unroll")                                                         \
    for (int m = 0; m < 4; ++m) {                                             \
      float a0_ = sd[m], a1_ = 0.f;                                           \
      a0_ = FDOT2(wihr[5*m+0], e0_, a0_);                                     \
      a1_ = FDOT2(wihr[5*m+1], e1_, a1_);                                     \
      a0_ = FDOT2(wihr[5*m+2], e2_, a0_);                                     \
      a1_ = FDOT2(wihr[5*m+3], e3_, a1_);                                     \
      a0_ = FDOT2(wihr[5*m+4], e4_, a0_);                                     \
      a1_ = FDOT2(whh[8*m+0], bc_h2(h0_.x), a1_);                             \
      a0_ = FDOT2(whh[8*m+1], bc_h2(h0_.y), a0_);                             \
      a1_ = FDOT2(whh[8*m+2], bc_h2(h0_.z), a1_);                             \
      a0_ = FDOT2(whh[8*m+3], bc_h2(h0_.w), a0_);                             \
      a1_ = FDOT2(whh[8*m+4], bc_h2(h1_.x), a1_);                             \
      a0_ = FDOT2(whh[8*m+5], bc_h2(h1_.y), a0_);                             \
      a1_ = FDOT2(whh[8*m+6], bc_h2(h1_.z), a1_);                             \
      a0_ = FDOT2(whh[8*m+7], bc_h2(h1_.w), a0_);                             \
      dA_[m] = a0_ + a1_;                                                     \
    }                                                                         \
    const float g0_ = dA_[0] + __shfl_xor(dA_[0], 32);                        \
    const float g1_ = dA_[1] + __shfl_xor(dA_[1], 32);                        \
    const float g2_ = dA_[2] + __shfl_xor(dA_[2], 32);                        \
    const float g3_ = dA_[3] + __shfl_xor(dA_[3], 32);                        \
    const float gi_ = sigm(g0_);                                              \
    const float gf_ = sigm(g1_);                                              \
    const float gg_ = tanh_f(g2_);                                            \
    const float go_ = sigm(g3_);                                              \
    c = fmaf(gf_, c, gi_ * gg_);                                              \
    const float hv_ = go_ * tanh_f(c);                                        \
    if (p == 0) sh_h[u] = (_Float16)hv_;                                      \
  }

// One wave per batch element. Lane l = (u = l&31, p = l>>5).
// K-split over W_ih and W_hh: lane owns gate rows {u+32m} x its half of
// [h20(20)|h(32)]. NO fences / barriers in the T-loop -> weight registers
// are loop-invariant (LDS and global are distinct address spaces).
template <bool GH>
__global__ __attribute__((amdgpu_waves_per_eu(4, 4))) __launch_bounds__(64)
void lstm_fused(
    const float* __restrict__ x,
    const float* __restrict__ fc1_w,
    const float* __restrict__ fc1_b,
    const unsigned int* __restrict__ ws,
    const float* __restrict__ fc2_w,
    const float* __restrict__ fc2_b,
    float* __restrict__ out)
{
    const int b = blockIdx.x;
    const int l = threadIdx.x;
    const int u = l & 31;
    const int p = l >> 5;

    __shared__ __align__(16) _Float16 sh_h[NH];    // 64 B

    // weights: loop-invariant loads from ws (global, const, restrict)
    h2t whh[32];
    {
        const uint4* wp = (const uint4*)(ws + WS_WHH + l * 32);
        #pragma unroll
        for (int g = 0; g < 8; ++g) {
            uint4 v = wp[g];
            whh[4*g+0] = bc_h2(v.x); whh[4*g+1] = bc_h2(v.y);
            whh[4*g+2] = bc_h2(v.z); whh[4*g+3] = bc_h2(v.w);
        }
    }
    h2t wihr[20];
    {
        const uint4* wp = (const uint4*)(ws + WS_WIH + l * 20);
        #pragma unroll
        for (int g = 0; g < 5; ++g) {
            uint4 v = wp[g];
            wihr[4*g+0] = bc_h2(v.x); wihr[4*g+1] = bc_h2(v.y);
            wihr[4*g+2] = bc_h2(v.z); wihr[4*g+3] = bc_h2(v.w);
        }
    }
    const float* biasf = (const float*)(ws + WS_BIAS);
    float sd[4];
    #pragma unroll
    for (int m = 0; m < 4; ++m) sd[m] = (p == 0) ? biasf[u + 32 * m] : 0.f;

    if (l < 16) ((unsigned int*)sh_h)[l] = 0u;   // h=0; DS FIFO orders vs reads
    float c = 0.f;

    if constexpr (GH) {
        const unsigned int* h20p = ws + WS_H20 + (size_t)b * TT * RSG;
        uint4 qa0, qa1; uint2 qa2;
#define LOADROW(Q0, Q1, Q2, t)                                                \
        { const unsigned int* rp_ = h20p + (size_t)(t) * RSG;                 \
          (Q0) = *(const uint4*)(rp_);                                        \
          (Q1) = *(const uint4*)(rp_ + 4);                                    \
          (Q2) = *(const uint2*)(rp_ + 8); }
        LOADROW(qa0, qa1, qa2, 0);
        for (int t = 0; t < TT; ++t) {
            uint4 nb0, nb1; uint2 nb2;
            const int tn = (t + 1 < TT) ? (t + 1) : t;
            LOADROW(nb0, nb1, nb2, tn);           // prefetch next row
            STEP(qa0, qa1, qa2);
            qa0 = nb0; qa1 = nb1; qa2 = nb2;
        }
#undef LOADROW
    } else {
        __shared__ __align__(16) unsigned int h20c[CH * RSG];   // 3 KB
        const float* xb = x + (size_t)b * (TT * IN);
        for (int tc = 0; tc < TT; tc += CH) {
            {   // refill: lane l computes h20 row for t = tc + l
                const int t = tc + l;
                if (t < TT) {
                    float xv[IN];
                    #pragma unroll
                    for (int i = 0; i < IN; ++i) xv[i] = xb[t * IN + i];
                    unsigned int ow[10];
                    #pragma unroll
                    for (int j = 0; j < FC1; j += 2) {
                        float a0 = fc1_b[j], a1 = fc1_b[j + 1];
                        #pragma unroll
                        for (int i = 0; i < IN; ++i) {
                            a0 = fmaf(fc1_w[j * IN + i],       xv[i], a0);
                            a1 = fmaf(fc1_w[(j + 1) * IN + i], xv[i], a1);
                        }
                        ow[j >> 1] = h2bits(fmaxf(a0, 0.f), fmaxf(a1, 0.f));
                    }
                    unsigned int* dst = h20c + l * RSG;
                    *(uint4*)(dst)     = uint4{ow[0], ow[1], ow[2], ow[3]};
                    *(uint4*)(dst + 4) = uint4{ow[4], ow[5], ow[6], ow[7]};
                    *(uint2*)(dst + 8) = uint2{ow[8], ow[9]};
                }
            }
            __syncthreads();                       // chunk boundary only
            const int te = (TT - tc < CH) ? (TT - tc) : CH;
            for (int k = 0; k < te; ++k) {
                const unsigned int* rp_ = h20c + k * RSG;
                uint4 q0 = *(const uint4*)(rp_);
                uint4 q1 = *(const uint4*)(rp_ + 4);
                uint2 q2 = *(const uint2*)(rp_ + 8);
                STEP(q0, q1, q2);
            }
            __syncthreads();
        }
    }

    __syncthreads();   // outside the loop; order final h writes vs epilogue
    if (l < 2) {
        float acc = fc2_b[l];
        #pragma unroll
        for (int k = 0; k < NH; ++k)
            acc = fmaf(fc2_w[l * NH + k], (float)sh_h[k], acc);
        out[(size_t)b * 2 + l] = acc;
    }
}

extern "C" void kernel_launch(void* const* d_in, const int* in_sizes, int n_in,
                              void* d_out, int out_size, void* d_ws, size_t ws_size,
                              hipStream_t stream) {
    const float* x     = (const float*)d_in[0];
    const float* fc1_w = (const float*)d_in[1];
    const float* fc1_b = (const float*)d_in[2];
    const float* w_ih  = (const float*)d_in[3];
    const float* w_hh  = (const float*)d_in[4];
    const float* b_ih  = (const float*)d_in[5];
    const float* b_hh  = (const float*)d_in[6];
    const float* fc2_w = (const float*)d_in[7];
    const float* fc2_b = (const float*)d_in[8];
    float* out = (float*)d_out;
    unsigned int* ws = (unsigned int*)d_ws;

    const int B = in_sizes[0] / (TT * IN);
    const int nrows = B * TT;
    const size_t need = ((size_t)WS_H20 + (size_t)nrows * RSG) * 4;

    prep_w<<<dim3(29), dim3(256), 0, stream>>>(w_ih, w_hh, b_ih, b_hh, ws);
    if (ws_size >= need) {
        prep_h20<<<dim3((nrows + 255) / 256), dim3(256), 0, stream>>>(
            x, fc1_w, fc1_b, ws, nrows);
        lstm_fused<true><<<dim3(B), dim3(64), 0, stream>>>(
            x, fc1_w, fc1_b, ws, fc2_w, fc2_b, out);
    } else {
        lstm_fused<false><<<dim3(B), dim3(64), 0, stream>>>(
            x, fc1_w, fc1_b, ws, fc2_w, fc2_b, out);
    }
}